// Round 4
// baseline (1583.880 us; speedup 1.0000x reference)
//
#include <hip/hip_runtime.h>
#include <cstdint>
#include <cstddef>

// GraphSAGE 3-layer, N=100000 nodes, E=1600000 edges, dims 64->64->64->32.
// Transform-then-aggregate (linearity of segment_sum). Edges binned once per
// launch into fixed-capacity dst-buckets of 32 nodes; aggregation fuses the
// per-bucket sort away by accumulating bf16 rows into LDS fp32 planes with
// ds_add_f32 (bank-conflict-free layout), then applies mean + residual + ELU.

constexpr int BW = 32;      // dst nodes per bucket
constexpr int LOGBW = 5;
constexpr int CAP = 640;    // bucket capacity; mean load = 512, sigma ~22.6
// NB = ceil(N/BW) = 3125 for N=100000 (hist array supports NB <= 4096)

__device__ inline unsigned short f2bf(float f) {
  unsigned u = __builtin_bit_cast(unsigned, f);
  u += 0x7FFFu + ((u >> 16) & 1u);          // round-to-nearest-even
  return (unsigned short)(u >> 16);
}
__device__ inline float bf2f(unsigned short b) {
  unsigned u = ((unsigned)b) << 16;
  return __builtin_bit_cast(float, u);
}

// ---------------- edge binning (single pass, fixed-capacity buckets) ------
// Per-block LDS histogram over its 8192-edge chunk, one global atomic per
// touched bucket to reserve a contiguous run, then scatter packed words
// (src | dstlocal<<17) into bucket-contiguous regions. bcur ends up holding
// the exact per-bucket edge count (used by bucket_gather).

__global__ __launch_bounds__(256) void bucket_bin(const int* __restrict__ src,
                                                  const int* __restrict__ dst,
                                                  int* __restrict__ bcur,
                                                  unsigned int* __restrict__ binned,
                                                  int NB, int E) {
  __shared__ int h[4096];
  for (int i = threadIdx.x; i < NB; i += 256) h[i] = 0;
  __syncthreads();
  int e0 = blockIdx.x * 8192;
  int e1 = min(E, e0 + 8192);
  for (int e = e0 + (int)threadIdx.x; e < e1; e += 256)
    atomicAdd(&h[dst[e] >> LOGBW], 1);
  __syncthreads();
  for (int i = threadIdx.x; i < NB; i += 256) {
    int c = h[i];
    h[i] = c ? (i * CAP + atomicAdd(&bcur[i], c)) : 0;  // slot -> abs cursor
  }
  __syncthreads();
  for (int e = e0 + (int)threadIdx.x; e < e1; e += 256) {
    int d = dst[e];
    int b = d >> LOGBW;
    int pos = atomicAdd(&h[b], 1);
    if (pos < (b + 1) * CAP)                 // overflow guard (never taken)
      binned[pos] = (unsigned)src[e] | ((unsigned)(d & (BW - 1)) << 17);
  }
}

// ---------------- fused dual GEMM: t = bf16(h@Wl) ; r = h@Wr + b ----------
// K = 64 fixed. Block: 64-row tile, thread tile 4 rows x 8 cols (4 t + 4 r).
// h and r_out may alias in-place — no __restrict__ on those two.

template <int DOUT>
__global__ __launch_bounds__(256) void gemm_dual(const float* h,
                                                 const float* __restrict__ Wl,
                                                 const float* __restrict__ Wr,
                                                 const float* __restrict__ bias,
                                                 unsigned short* __restrict__ t_out,
                                                 float* r_out, int N) {
  constexpr int TC = 2 * DOUT;
  constexpr int NC = TC / 8;
  constexpr int NT = 16 * NC;
  __shared__ float hs[64 * 68];
  __shared__ float wsh[64 * TC];

  const int tid = threadIdx.x;
  const int row0 = blockIdx.x * 64;

  for (int idx = tid; idx < 64 * 16; idx += NT) {
    int r = idx >> 4, c4 = (idx & 15) << 2;
    int gr = row0 + r;
    if (gr > N - 1) gr = N - 1;
    float4 v = *(const float4*)&h[(size_t)gr * 64 + c4];
    *(float4*)&hs[r * 68 + c4] = v;
  }
  for (int idx = tid; idx < 16 * DOUT; idx += NT) {
    int f = idx << 2;
    int k = f / DOUT, c = f % DOUT;
    *(float4*)&wsh[k * TC + c] = *(const float4*)&Wl[f];
    *(float4*)&wsh[k * TC + DOUT + c] = *(const float4*)&Wr[f];
  }
  __syncthreads();

  const int cid = tid % NC;
  const int rid = tid / NC;
  float acc[4][8];
#pragma unroll
  for (int i = 0; i < 4; ++i)
#pragma unroll
    for (int m = 0; m < 8; ++m) acc[i][m] = 0.f;

#pragma unroll 8
  for (int k = 0; k < 64; ++k) {
    float4 w0 = *(const float4*)&wsh[k * TC + 4 * cid];
    float4 w1 = *(const float4*)&wsh[k * TC + DOUT + 4 * cid];
#pragma unroll
    for (int i = 0; i < 4; ++i) {
      float hv = hs[(4 * rid + i) * 68 + k];
      acc[i][0] += hv * w0.x; acc[i][1] += hv * w0.y;
      acc[i][2] += hv * w0.z; acc[i][3] += hv * w0.w;
      acc[i][4] += hv * w1.x; acc[i][5] += hv * w1.y;
      acc[i][6] += hv * w1.z; acc[i][7] += hv * w1.w;
    }
  }

  float4 bv = *(const float4*)&bias[4 * cid];
#pragma unroll
  for (int i = 0; i < 4; ++i) {
    int gr = row0 + 4 * rid + i;
    if (gr < N) {
      ushort4 tv;
      tv.x = f2bf(acc[i][0]); tv.y = f2bf(acc[i][1]);
      tv.z = f2bf(acc[i][2]); tv.w = f2bf(acc[i][3]);
      *(ushort4*)&t_out[(size_t)gr * DOUT + 4 * cid] = tv;
      *(float4*)&r_out[(size_t)gr * DOUT + 4 * cid] =
          make_float4(acc[i][4] + bv.x, acc[i][5] + bv.y,
                      acc[i][6] + bv.z, acc[i][7] + bv.w);
    }
  }
}

// ------ fused bucket aggregation: out = elu?(mean_nbr(t) + r) -------------
// One block per bucket (32 dst nodes). Unsorted bucket edge list consumed
// directly; bf16-pair rows accumulated into two fp32 LDS planes via
// ds_add_f32. Plane layout acc[dl*L + lane] -> bank == lane (conflict-free).
// L = DOUT/2 lanes per edge-subgroup; unroll 8 for memory-level parallelism.
// r and out alias in place; no restrict on those two.

template <int DOUT, bool DO_ELU>
__global__ __launch_bounds__(256) void bucket_gather(const unsigned int* __restrict__ t,
                                                     const float* r,
                                                     const int* __restrict__ bcur,
                                                     const unsigned int* __restrict__ binned,
                                                     float* out, int N) {
  constexpr int L = DOUT / 2;          // uints per row: 32 or 16
  constexpr int SG = 256 / L;          // edge-subgroups per block: 8 or 16
  __shared__ float accL[BW * L];
  __shared__ float accH[BW * L];
  __shared__ int cnt[BW];

  const int tid = threadIdx.x;
  const int b = blockIdx.x;
  for (int i = tid; i < BW * L; i += 256) { accL[i] = 0.f; accH[i] = 0.f; }
  if (tid < BW) cnt[tid] = 0;
  __syncthreads();

  const int ec = min(bcur[b], CAP);
  const unsigned* eb = binned + (size_t)b * CAP;
  const int sg = tid / L;
  const int lane = tid % L;

  const int full = (ec / (SG * 8)) * (SG * 8);
  for (int k = 0; k < full; k += SG * 8) {
    const uint4* p = (const uint4*)(eb + k + sg * 8);
    uint4 wa = p[0], wb = p[1];
    unsigned w[8] = {wa.x, wa.y, wa.z, wa.w, wb.x, wb.y, wb.z, wb.w};
    unsigned v[8];
    int dl[8];
#pragma unroll
    for (int j = 0; j < 8; ++j) {
      dl[j] = (int)(w[j] >> 17);
      v[j] = t[(size_t)(w[j] & 0x1FFFFu) * L + lane];
    }
#pragma unroll
    for (int j = 0; j < 8; ++j) {
      if (lane == 0) atomicAdd(&cnt[dl[j]], 1);
      atomicAdd(&accL[dl[j] * L + lane], bf2f((unsigned short)(v[j] & 0xFFFFu)));
      atomicAdd(&accH[dl[j] * L + lane], bf2f((unsigned short)(v[j] >> 16)));
    }
  }
  for (int e = full + sg; e < ec; e += SG) {
    unsigned w = eb[e];
    int dl = (int)(w >> 17);
    unsigned v = t[(size_t)(w & 0x1FFFFu) * L + lane];
    if (lane == 0) atomicAdd(&cnt[dl], 1);
    atomicAdd(&accL[dl * L + lane], bf2f((unsigned short)(v & 0xFFFFu)));
    atomicAdd(&accH[dl * L + lane], bf2f((unsigned short)(v >> 16)));
  }
  __syncthreads();

  for (int i = tid; i < BW * L; i += 256) {
    int nl = i / L, l = i % L;
    int gn = b * BW + nl;
    if (gn < N) {
      float di = 1.0f / (float)max(cnt[nl], 1);
      float2 rv = *(const float2*)&r[(size_t)gn * DOUT + 2 * l];
      float a0 = accL[nl * L + l] * di + rv.x;
      float a1 = accH[nl * L + l] * di + rv.y;
      if (DO_ELU) {
        a0 = a0 > 0.f ? a0 : (expf(a0) - 1.f);
        a1 = a1 > 0.f ? a1 : (expf(a1) - 1.f);
      }
      *(float2*)&out[(size_t)gn * DOUT + 2 * l] = make_float2(a0, a1);
    }
  }
}

// ---------------- launch ----------------

extern "C" void kernel_launch(void* const* d_in, const int* in_sizes, int n_in,
                              void* d_out, int out_size, void* d_ws, size_t ws_size,
                              hipStream_t stream) {
  const float* x   = (const float*)d_in[0];
  const int*   ei  = (const int*)d_in[1];
  const float* Wl0 = (const float*)d_in[2];
  const float* Wr0 = (const float*)d_in[3];
  const float* b0  = (const float*)d_in[4];
  const float* Wl1 = (const float*)d_in[5];
  const float* Wr1 = (const float*)d_in[6];
  const float* b1  = (const float*)d_in[7];
  const float* Wl2 = (const float*)d_in[8];
  const float* Wr2 = (const float*)d_in[9];
  const float* b2  = (const float*)d_in[10];
  float* out = (float*)d_out;

  const int N = in_sizes[0] / 64;   // 100000
  const int E = in_sizes[1] / 2;    // 1600000
  const int* srcv = ei;
  const int* dstv = ei + E;
  const int NB = (N + BW - 1) >> LOGBW;   // 3125

  auto al = [](size_t v) { return (v + 255) & ~(size_t)255; };
  char* w = (char*)d_ws;
  size_t oBcur = 0;
  size_t oBin  = oBcur + al(4 * (size_t)NB);
  size_t oP    = oBin + al(4 * (size_t)NB * CAP);
  size_t oQ    = oP + al(2 * (size_t)N * 64);
  // total = oQ + 4*N*64  (~46.5 MiB)

  int*            bcur   = (int*)(w + oBcur);
  unsigned*       binned = (unsigned*)(w + oBin);
  unsigned short* P      = (unsigned short*)(w + oP);   // bf16 t buffer
  float*          Q      = (float*)(w + oQ);

  hipMemsetAsync(bcur, 0, (size_t)NB * 4, stream);

  int bbl = (E + 8191) / 8192;   // 196
  bucket_bin<<<bbl, 256, 0, stream>>>(srcv, dstv, bcur, binned, NB, E);

  int gb = (N + 63) / 64;
  gemm_dual<64><<<gb, 256, 0, stream>>>(x, Wl0, Wr0, b0, P, Q, N);
  bucket_gather<64, true><<<NB, 256, 0, stream>>>((const unsigned*)P, Q, bcur, binned, Q, N);
  gemm_dual<64><<<gb, 256, 0, stream>>>(Q, Wl1, Wr1, b1, P, Q, N);
  bucket_gather<64, true><<<NB, 256, 0, stream>>>((const unsigned*)P, Q, bcur, binned, Q, N);
  gemm_dual<32><<<gb, 128, 0, stream>>>(Q, Wl2, Wr2, b2, P, out, N);
  bucket_gather<32, false><<<NB, 256, 0, stream>>>((const unsigned*)P, out, bcur, binned, out, N);
}

// Round 5
// 327.948 us; speedup vs baseline: 4.8297x; 4.8297x over previous
//
#include <hip/hip_runtime.h>
#include <cstdint>
#include <cstddef>

// GraphSAGE 3-layer, N=100000 nodes, E=1600000 edges, dims 64->64->64->32.
// Transform-then-aggregate; CSR built once per launch via bucketed counting
// sort; gather reads bf16-packed transformed features (uint2 per lane,
// 16 lanes/node, 8-edge unroll for MLP), accumulates fp32.
// NOTE round-4 post-mortem: LDS-atomic aggregation (ds_add_f32) is 12x slower
// than this CSR gather — do not revisit.

constexpr int BW = 128;      // nodes per bucket (power of 2)
constexpr int LOGBW = 7;
// NB = ceil(N/BW) = 782 for N=100000; LDS hist arrays sized 1024 (N<=131072).

__device__ inline unsigned short f2bf(float f) {
  unsigned u = __builtin_bit_cast(unsigned, f);
  u += 0x7FFFu + ((u >> 16) & 1u);          // round-to-nearest-even
  return (unsigned short)(u >> 16);
}
__device__ inline float bf2f(unsigned short b) {
  unsigned u = ((unsigned)b) << 16;
  return __builtin_bit_cast(float, u);
}

// ---------------- CSR build: bucketed counting sort ----------------

__global__ __launch_bounds__(256) void bucket_count(const int* __restrict__ dst,
                                                    int* __restrict__ bcnt,
                                                    int NB, int E) {
  __shared__ int h[1024];
  for (int i = threadIdx.x; i < NB; i += 256) h[i] = 0;
  __syncthreads();
  int e0 = blockIdx.x * 4096;
  int e1 = min(E, e0 + 4096);
  for (int e = e0 + (int)threadIdx.x; e < e1; e += 256)
    atomicAdd(&h[dst[e] >> LOGBW], 1);
  __syncthreads();
  for (int i = threadIdx.x; i < NB; i += 256) {
    int c = h[i];
    if (c) atomicAdd(&bcnt[i], c);
  }
}

__global__ __launch_bounds__(1024) void bucket_scan(const int* __restrict__ bcnt,
                                                    int* __restrict__ boff,
                                                    int* __restrict__ bcur,
                                                    int* __restrict__ rowptr,
                                                    int NB, int N, int E) {
  __shared__ int sh[1024];
  int tid = threadIdx.x;
  int v = (tid < NB) ? bcnt[tid] : 0;
  sh[tid] = v;
  __syncthreads();
  for (int off = 1; off < 1024; off <<= 1) {
    int x = sh[tid];
    if (tid >= off) x += sh[tid - off];
    __syncthreads();
    sh[tid] = x;
    __syncthreads();
  }
  if (tid < NB) {
    int ex = sh[tid] - v;
    boff[tid] = ex;
    bcur[tid] = ex;
  }
  if (tid == 0) {
    boff[NB] = E;
    rowptr[N] = E;
  }
}

__global__ __launch_bounds__(256) void bucket_bin(const int* __restrict__ src,
                                                  const int* __restrict__ dst,
                                                  int* __restrict__ bcur,
                                                  unsigned int* __restrict__ binned,
                                                  int NB, int E) {
  __shared__ int h[1024];
  for (int i = threadIdx.x; i < NB; i += 256) h[i] = 0;
  __syncthreads();
  int e0 = blockIdx.x * 4096;
  int e1 = min(E, e0 + 4096);
  for (int e = e0 + (int)threadIdx.x; e < e1; e += 256)
    atomicAdd(&h[dst[e] >> LOGBW], 1);
  __syncthreads();
  for (int i = threadIdx.x; i < NB; i += 256) {
    int c = h[i];
    h[i] = c ? atomicAdd(&bcur[i], c) : 0;   // hist slot becomes write cursor
  }
  __syncthreads();
  for (int e = e0 + (int)threadIdx.x; e < e1; e += 256) {
    int d = dst[e];
    int b = d >> LOGBW;
    int pos = atomicAdd(&h[b], 1);
    binned[pos] = (unsigned)src[e] | ((unsigned)(d & (BW - 1)) << 17);
  }
}

__global__ __launch_bounds__(256) void bucket_csr(const unsigned int* __restrict__ binned,
                                                  const int* __restrict__ boff,
                                                  int* __restrict__ rowptr,
                                                  float* __restrict__ deg_inv,
                                                  int* __restrict__ colidx,
                                                  int N) {
  __shared__ int cnt[BW];
  __shared__ int sc[BW];
  __shared__ int cur[BW];
  int b = blockIdx.x;
  int tid = threadIdx.x;
  if (tid < BW) cnt[tid] = 0;
  __syncthreads();
  int e0 = boff[b], e1 = boff[b + 1];
  for (int e = e0 + tid; e < e1; e += 256)
    atomicAdd(&cnt[binned[e] >> 17], 1);
  __syncthreads();
  int v = (tid < BW) ? cnt[tid] : 0;
  if (tid < BW) sc[tid] = v;
  __syncthreads();
  for (int off = 1; off < BW; off <<= 1) {
    int y = 0;
    if (tid < BW) {
      y = sc[tid];
      if (tid >= off) y += sc[tid - off];
    }
    __syncthreads();
    if (tid < BW) sc[tid] = y;
    __syncthreads();
  }
  if (tid < BW) {
    int ex = sc[tid] - v;
    cur[tid] = ex;
    int gn = b * BW + tid;
    if (gn < N) {
      rowptr[gn] = e0 + ex;
      deg_inv[gn] = 1.0f / (float)(v > 1 ? v : 1);
    }
  }
  __syncthreads();
  for (int e = e0 + tid; e < e1; e += 256) {
    unsigned p = binned[e];
    int dl = (int)(p >> 17);
    int s = (int)(p & 0x1FFFFu);
    int l = atomicAdd(&cur[dl], 1);
    colidx[e0 + l] = s;
  }
}

// ---------------- fused dual GEMM: t = bf16(h@Wl) ; r = h@Wr + b ----------
// K = 64 fixed. Block: 64-row tile, thread tile 4 rows x 8 cols (4 t + 4 r).
// h and r_out may alias in-place — no __restrict__ on those two.

template <int DOUT>
__global__ __launch_bounds__(256) void gemm_dual(const float* h,
                                                 const float* __restrict__ Wl,
                                                 const float* __restrict__ Wr,
                                                 const float* __restrict__ bias,
                                                 unsigned short* __restrict__ t_out,
                                                 float* r_out, int N) {
  constexpr int TC = 2 * DOUT;
  constexpr int NC = TC / 8;
  constexpr int NT = 16 * NC;
  __shared__ float hs[64 * 68];
  __shared__ float wsh[64 * TC];

  const int tid = threadIdx.x;
  const int row0 = blockIdx.x * 64;

  for (int idx = tid; idx < 64 * 16; idx += NT) {
    int r = idx >> 4, c4 = (idx & 15) << 2;
    int gr = row0 + r;
    if (gr > N - 1) gr = N - 1;
    float4 v = *(const float4*)&h[(size_t)gr * 64 + c4];
    *(float4*)&hs[r * 68 + c4] = v;
  }
  for (int idx = tid; idx < 16 * DOUT; idx += NT) {
    int f = idx << 2;
    int k = f / DOUT, c = f % DOUT;
    *(float4*)&wsh[k * TC + c] = *(const float4*)&Wl[f];
    *(float4*)&wsh[k * TC + DOUT + c] = *(const float4*)&Wr[f];
  }
  __syncthreads();

  const int cid = tid % NC;
  const int rid = tid / NC;
  float acc[4][8];
#pragma unroll
  for (int i = 0; i < 4; ++i)
#pragma unroll
    for (int m = 0; m < 8; ++m) acc[i][m] = 0.f;

#pragma unroll 8
  for (int k = 0; k < 64; ++k) {
    float4 w0 = *(const float4*)&wsh[k * TC + 4 * cid];
    float4 w1 = *(const float4*)&wsh[k * TC + DOUT + 4 * cid];
#pragma unroll
    for (int i = 0; i < 4; ++i) {
      float hv = hs[(4 * rid + i) * 68 + k];
      acc[i][0] += hv * w0.x; acc[i][1] += hv * w0.y;
      acc[i][2] += hv * w0.z; acc[i][3] += hv * w0.w;
      acc[i][4] += hv * w1.x; acc[i][5] += hv * w1.y;
      acc[i][6] += hv * w1.z; acc[i][7] += hv * w1.w;
    }
  }

  float4 bv = *(const float4*)&bias[4 * cid];
#pragma unroll
  for (int i = 0; i < 4; ++i) {
    int gr = row0 + 4 * rid + i;
    if (gr < N) {
      ushort4 tv;
      tv.x = f2bf(acc[i][0]); tv.y = f2bf(acc[i][1]);
      tv.z = f2bf(acc[i][2]); tv.w = f2bf(acc[i][3]);
      *(ushort4*)&t_out[(size_t)gr * DOUT + 4 * cid] = tv;
      *(float4*)&r_out[(size_t)gr * DOUT + 4 * cid] =
          make_float4(acc[i][4] + bv.x, acc[i][5] + bv.y,
                      acc[i][6] + bv.z, acc[i][7] + bv.w);
    }
  }
}

// ------ gather: out = elu?(deg_inv * sum t[src] + r[dst]), t is bf16 ------
// DOUT/4 lanes per node; each lane owns 4 features via one uint2 (8 B) load
// per edge — a 64-lane wave serves 4 nodes, 8-edge unroll => up to 32 row
// loads in flight per wave. r and out alias in place; no restrict there.

template <int DOUT, bool DO_ELU>
__global__ __launch_bounds__(256) void gather_mean(const uint2* __restrict__ t,
                                                   const float* r,
                                                   const float* __restrict__ deg_inv,
                                                   const int* __restrict__ rowptr,
                                                   const int* __restrict__ colidx,
                                                   float* out, int N) {
  constexpr int L = DOUT / 4;                 // uint2 lanes per node: 16 or 8
  int node = blockIdx.x * (256 / L) + threadIdx.x / L;
  int lane = threadIdx.x & (L - 1);
  if (node >= N) return;
  int b = rowptr[node];
  int e = rowptr[node + 1];
  float s0 = 0.f, s1 = 0.f, s2 = 0.f, s3 = 0.f;
  int i = b;
  for (; i + 8 <= e; i += 8) {
    uint2 v[8];
#pragma unroll
    for (int j = 0; j < 8; ++j)
      v[j] = t[(size_t)colidx[i + j] * L + lane];
#pragma unroll
    for (int j = 0; j < 8; ++j) {
      s0 += bf2f((unsigned short)(v[j].x & 0xFFFFu));
      s1 += bf2f((unsigned short)(v[j].x >> 16));
      s2 += bf2f((unsigned short)(v[j].y & 0xFFFFu));
      s3 += bf2f((unsigned short)(v[j].y >> 16));
    }
  }
  for (; i < e; ++i) {
    uint2 v = t[(size_t)colidx[i] * L + lane];
    s0 += bf2f((unsigned short)(v.x & 0xFFFFu));
    s1 += bf2f((unsigned short)(v.x >> 16));
    s2 += bf2f((unsigned short)(v.y & 0xFFFFu));
    s3 += bf2f((unsigned short)(v.y >> 16));
  }
  float dv = deg_inv[node];
  float4 rv = *(const float4*)&r[(size_t)node * DOUT + 4 * lane];
  float a0 = s0 * dv + rv.x;
  float a1 = s1 * dv + rv.y;
  float a2 = s2 * dv + rv.z;
  float a3 = s3 * dv + rv.w;
  if (DO_ELU) {
    a0 = a0 > 0.f ? a0 : (expf(a0) - 1.f);
    a1 = a1 > 0.f ? a1 : (expf(a1) - 1.f);
    a2 = a2 > 0.f ? a2 : (expf(a2) - 1.f);
    a3 = a3 > 0.f ? a3 : (expf(a3) - 1.f);
  }
  *(float4*)&out[(size_t)node * DOUT + 4 * lane] = make_float4(a0, a1, a2, a3);
}

// ---------------- launch ----------------

extern "C" void kernel_launch(void* const* d_in, const int* in_sizes, int n_in,
                              void* d_out, int out_size, void* d_ws, size_t ws_size,
                              hipStream_t stream) {
  const float* x   = (const float*)d_in[0];
  const int*   ei  = (const int*)d_in[1];
  const float* Wl0 = (const float*)d_in[2];
  const float* Wr0 = (const float*)d_in[3];
  const float* b0  = (const float*)d_in[4];
  const float* Wl1 = (const float*)d_in[5];
  const float* Wr1 = (const float*)d_in[6];
  const float* b1  = (const float*)d_in[7];
  const float* Wl2 = (const float*)d_in[8];
  const float* Wr2 = (const float*)d_in[9];
  const float* b2  = (const float*)d_in[10];
  float* out = (float*)d_out;

  const int N = in_sizes[0] / 64;   // 100000
  const int E = in_sizes[1] / 2;    // 1600000
  const int* srcv = ei;
  const int* dstv = ei + E;
  const int NB = (N + BW - 1) >> LOGBW;   // 782

  auto al = [](size_t v) { return (v + 255) & ~(size_t)255; };
  char* w = (char*)d_ws;
  size_t oBcnt = 0;
  size_t oBoff = oBcnt + al(4 * (size_t)NB);
  size_t oBcur = oBoff + al(4 * (size_t)(NB + 1));
  size_t oRow  = oBcur + al(4 * (size_t)NB);
  size_t oDinv = oRow + al(4 * (size_t)(N + 1));
  size_t oBin  = oDinv + al(4 * (size_t)N);
  size_t oCol  = oBin + al(4 * (size_t)E);
  size_t oP    = oCol + al(4 * (size_t)E);
  size_t oQ    = oP + al(2 * (size_t)N * 64);   // P is bf16
  // total = oQ + 4*N*64  (~52 MiB)

  int*            bcnt    = (int*)(w + oBcnt);
  int*            boff    = (int*)(w + oBoff);
  int*            bcur    = (int*)(w + oBcur);
  int*            rowptr  = (int*)(w + oRow);
  float*          deg_inv = (float*)(w + oDinv);
  unsigned*       binned  = (unsigned*)(w + oBin);
  int*            colidx  = (int*)(w + oCol);
  unsigned short* P       = (unsigned short*)(w + oP);   // bf16 t buffer
  float*          Q       = (float*)(w + oQ);

  hipMemsetAsync(bcnt, 0, (size_t)NB * 4, stream);

  int cbl = (E + 4095) / 4096;
  bucket_count<<<cbl, 256, 0, stream>>>(dstv, bcnt, NB, E);
  bucket_scan<<<1, 1024, 0, stream>>>(bcnt, boff, bcur, rowptr, NB, N, E);
  bucket_bin<<<cbl, 256, 0, stream>>>(srcv, dstv, bcur, binned, NB, E);
  bucket_csr<<<NB, 256, 0, stream>>>(binned, boff, rowptr, deg_inv, colidx, N);

  int gb = (N + 63) / 64;
  gemm_dual<64><<<gb, 256, 0, stream>>>(x, Wl0, Wr0, b0, P, Q, N);
  gather_mean<64, true><<<(N + 15) / 16, 256, 0, stream>>>((const uint2*)P, Q, deg_inv, rowptr, colidx, Q, N);
  gemm_dual<64><<<gb, 256, 0, stream>>>(Q, Wl1, Wr1, b1, P, Q, N);
  gather_mean<64, true><<<(N + 15) / 16, 256, 0, stream>>>((const uint2*)P, Q, deg_inv, rowptr, colidx, Q, N);
  gemm_dual<32><<<gb, 128, 0, stream>>>(Q, Wl2, Wr2, b2, P, out, N);
  gather_mean<32, false><<<(N + 31) / 32, 256, 0, stream>>>((const uint2*)P, out, deg_inv, rowptr, colidx, out, N);
}

// Round 6
// 323.995 us; speedup vs baseline: 4.8886x; 1.0122x over previous
//
#include <hip/hip_runtime.h>
#include <cstdint>
#include <cstddef>

// GraphSAGE 3-layer, N=100000 nodes, E=1600000 edges, dims 64->64->64->32.
// Transform-then-aggregate; padded-CSR built once per launch (2 kernels:
// bin + per-bucket sort), gather reads bf16-packed transformed features
// (uint2 per lane, 16 lanes/node, 8-edge unroll), accumulates fp32.
// R4 post-mortem: LDS-atomic aggregation (ds_add_f32) is 12x slower than the
// CSR gather — do not revisit.
// R6: padded CSR (fixed-capacity buckets) removes bucket_count+bucket_scan;
// bucket_bin chunk 8192->2048 fixes 11.8% occupancy.

constexpr int BW = 128;      // dst nodes per bucket (power of 2)
constexpr int LOGBW = 7;
constexpr int CAPB = 2560;   // bucket capacity; mean 2048, sigma ~45 (~11σ)
// NB = ceil(N/BW) = 782 for N=100000; hist array supports NB <= 1024.

__device__ inline unsigned short f2bf(float f) {
  unsigned u = __builtin_bit_cast(unsigned, f);
  u += 0x7FFFu + ((u >> 16) & 1u);          // round-to-nearest-even
  return (unsigned short)(u >> 16);
}
__device__ inline float bf2f(unsigned short b) {
  unsigned u = ((unsigned)b) << 16;
  return __builtin_bit_cast(float, u);
}

// ---------------- edge binning (single pass, fixed-capacity buckets) ------
// 2048-edge chunks -> 782 blocks. LDS hist over buckets, one global atomic
// per touched bucket to reserve a run, scatter packed (src | dl<<17) words
// into the bucket's padded region. bcur ends holding exact bucket counts.

__global__ __launch_bounds__(256) void bucket_bin(const int* __restrict__ src,
                                                  const int* __restrict__ dst,
                                                  int* __restrict__ bcur,
                                                  unsigned int* __restrict__ binned,
                                                  int NB, int E) {
  __shared__ int h[1024];
  for (int i = threadIdx.x; i < NB; i += 256) h[i] = 0;
  __syncthreads();
  int e0 = blockIdx.x * 2048;
  int e1 = min(E, e0 + 2048);
  for (int e = e0 + (int)threadIdx.x; e < e1; e += 256)
    atomicAdd(&h[dst[e] >> LOGBW], 1);
  __syncthreads();
  for (int i = threadIdx.x; i < NB; i += 256) {
    int c = h[i];
    h[i] = c ? (i * CAPB + atomicAdd(&bcur[i], c)) : 0;  // slot -> abs cursor
  }
  __syncthreads();
  for (int e = e0 + (int)threadIdx.x; e < e1; e += 256) {
    int d = dst[e];
    int b = d >> LOGBW;
    int pos = atomicAdd(&h[b], 1);
    if (pos < (b + 1) * CAPB)                 // overflow guard (never taken)
      binned[pos] = (unsigned)src[e] | ((unsigned)(d & (BW - 1)) << 17);
  }
}

// ---------------- per-bucket sort -> padded CSR ---------------------------
// One block per bucket: LDS degree count, local exclusive scan, write
// rowstart/deg/deg_inv, scatter src into bucket-local colidx span.

__global__ __launch_bounds__(256) void bucket_csr(const unsigned int* __restrict__ binned,
                                                  const int* __restrict__ bcur,
                                                  int* __restrict__ rowstart,
                                                  int* __restrict__ degarr,
                                                  float* __restrict__ deg_inv,
                                                  int* __restrict__ colidx,
                                                  int N) {
  __shared__ int cnt[BW];
  __shared__ int sc[BW];
  __shared__ int cur[BW];
  int b = blockIdx.x;
  int tid = threadIdx.x;
  if (tid < BW) cnt[tid] = 0;
  __syncthreads();
  const int ec = min(bcur[b], CAPB);
  const int base = b * CAPB;
  for (int e = tid; e < ec; e += 256)
    atomicAdd(&cnt[binned[base + e] >> 17], 1);
  __syncthreads();
  int v = (tid < BW) ? cnt[tid] : 0;
  if (tid < BW) sc[tid] = v;
  __syncthreads();
  for (int off = 1; off < BW; off <<= 1) {
    int y = 0;
    if (tid < BW) {
      y = sc[tid];
      if (tid >= off) y += sc[tid - off];
    }
    __syncthreads();
    if (tid < BW) sc[tid] = y;
    __syncthreads();
  }
  if (tid < BW) {
    int ex = sc[tid] - v;                     // exclusive prefix
    cur[tid] = ex;
    int gn = b * BW + tid;
    if (gn < N) {
      rowstart[gn] = base + ex;
      degarr[gn] = v;
      deg_inv[gn] = 1.0f / (float)(v > 1 ? v : 1);
    }
  }
  __syncthreads();
  for (int e = tid; e < ec; e += 256) {
    unsigned p = binned[base + e];
    int dl = (int)(p >> 17);
    int s = (int)(p & 0x1FFFFu);
    int l = atomicAdd(&cur[dl], 1);
    colidx[base + l] = s;
  }
}

// ---------------- fused dual GEMM: t = bf16(h@Wl) ; r = h@Wr + b ----------
// K = 64 fixed. Block: 64-row tile, thread tile 4 rows x 8 cols (4 t + 4 r).
// h and r_out may alias in-place — no __restrict__ on those two.

template <int DOUT>
__global__ __launch_bounds__(256) void gemm_dual(const float* h,
                                                 const float* __restrict__ Wl,
                                                 const float* __restrict__ Wr,
                                                 const float* __restrict__ bias,
                                                 unsigned short* __restrict__ t_out,
                                                 float* r_out, int N) {
  constexpr int TC = 2 * DOUT;
  constexpr int NC = TC / 8;
  constexpr int NT = 16 * NC;
  __shared__ float hs[64 * 68];
  __shared__ float wsh[64 * TC];

  const int tid = threadIdx.x;
  const int row0 = blockIdx.x * 64;

  for (int idx = tid; idx < 64 * 16; idx += NT) {
    int r = idx >> 4, c4 = (idx & 15) << 2;
    int gr = row0 + r;
    if (gr > N - 1) gr = N - 1;
    float4 v = *(const float4*)&h[(size_t)gr * 64 + c4];
    *(float4*)&hs[r * 68 + c4] = v;
  }
  for (int idx = tid; idx < 16 * DOUT; idx += NT) {
    int f = idx << 2;
    int k = f / DOUT, c = f % DOUT;
    *(float4*)&wsh[k * TC + c] = *(const float4*)&Wl[f];
    *(float4*)&wsh[k * TC + DOUT + c] = *(const float4*)&Wr[f];
  }
  __syncthreads();

  const int cid = tid % NC;
  const int rid = tid / NC;
  float acc[4][8];
#pragma unroll
  for (int i = 0; i < 4; ++i)
#pragma unroll
    for (int m = 0; m < 8; ++m) acc[i][m] = 0.f;

#pragma unroll 8
  for (int k = 0; k < 64; ++k) {
    float4 w0 = *(const float4*)&wsh[k * TC + 4 * cid];
    float4 w1 = *(const float4*)&wsh[k * TC + DOUT + 4 * cid];
#pragma unroll
    for (int i = 0; i < 4; ++i) {
      float hv = hs[(4 * rid + i) * 68 + k];
      acc[i][0] += hv * w0.x; acc[i][1] += hv * w0.y;
      acc[i][2] += hv * w0.z; acc[i][3] += hv * w0.w;
      acc[i][4] += hv * w1.x; acc[i][5] += hv * w1.y;
      acc[i][6] += hv * w1.z; acc[i][7] += hv * w1.w;
    }
  }

  float4 bv = *(const float4*)&bias[4 * cid];
#pragma unroll
  for (int i = 0; i < 4; ++i) {
    int gr = row0 + 4 * rid + i;
    if (gr < N) {
      ushort4 tv;
      tv.x = f2bf(acc[i][0]); tv.y = f2bf(acc[i][1]);
      tv.z = f2bf(acc[i][2]); tv.w = f2bf(acc[i][3]);
      *(ushort4*)&t_out[(size_t)gr * DOUT + 4 * cid] = tv;
      *(float4*)&r_out[(size_t)gr * DOUT + 4 * cid] =
          make_float4(acc[i][4] + bv.x, acc[i][5] + bv.y,
                      acc[i][6] + bv.z, acc[i][7] + bv.w);
    }
  }
}

// ------ gather: out = elu?(deg_inv * sum t[src] + r[dst]), t is bf16 ------
// DOUT/4 lanes per node; each lane owns 4 features via one uint2 (8 B) load
// per edge — a 64-lane wave serves 4 nodes, 8-edge unroll => up to 32 row
// loads in flight per wave. r and out alias in place; no restrict there.

template <int DOUT, bool DO_ELU>
__global__ __launch_bounds__(256) void gather_mean(const uint2* __restrict__ t,
                                                   const float* r,
                                                   const float* __restrict__ deg_inv,
                                                   const int* __restrict__ rowstart,
                                                   const int* __restrict__ degarr,
                                                   const int* __restrict__ colidx,
                                                   float* out, int N) {
  constexpr int L = DOUT / 4;                 // uint2 lanes per node: 16 or 8
  int node = blockIdx.x * (256 / L) + threadIdx.x / L;
  int lane = threadIdx.x & (L - 1);
  if (node >= N) return;
  int b = rowstart[node];
  int e = b + degarr[node];
  float s0 = 0.f, s1 = 0.f, s2 = 0.f, s3 = 0.f;
  int i = b;
  for (; i + 8 <= e; i += 8) {
    uint2 v[8];
#pragma unroll
    for (int j = 0; j < 8; ++j)
      v[j] = t[(size_t)colidx[i + j] * L + lane];
#pragma unroll
    for (int j = 0; j < 8; ++j) {
      s0 += bf2f((unsigned short)(v[j].x & 0xFFFFu));
      s1 += bf2f((unsigned short)(v[j].x >> 16));
      s2 += bf2f((unsigned short)(v[j].y & 0xFFFFu));
      s3 += bf2f((unsigned short)(v[j].y >> 16));
    }
  }
  for (; i < e; ++i) {
    uint2 v = t[(size_t)colidx[i] * L + lane];
    s0 += bf2f((unsigned short)(v.x & 0xFFFFu));
    s1 += bf2f((unsigned short)(v.x >> 16));
    s2 += bf2f((unsigned short)(v.y & 0xFFFFu));
    s3 += bf2f((unsigned short)(v.y >> 16));
  }
  float dv = deg_inv[node];
  float4 rv = *(const float4*)&r[(size_t)node * DOUT + 4 * lane];
  float a0 = s0 * dv + rv.x;
  float a1 = s1 * dv + rv.y;
  float a2 = s2 * dv + rv.z;
  float a3 = s3 * dv + rv.w;
  if (DO_ELU) {
    a0 = a0 > 0.f ? a0 : (expf(a0) - 1.f);
    a1 = a1 > 0.f ? a1 : (expf(a1) - 1.f);
    a2 = a2 > 0.f ? a2 : (expf(a2) - 1.f);
    a3 = a3 > 0.f ? a3 : (expf(a3) - 1.f);
  }
  *(float4*)&out[(size_t)node * DOUT + 4 * lane] = make_float4(a0, a1, a2, a3);
}

// ---------------- launch ----------------

extern "C" void kernel_launch(void* const* d_in, const int* in_sizes, int n_in,
                              void* d_out, int out_size, void* d_ws, size_t ws_size,
                              hipStream_t stream) {
  const float* x   = (const float*)d_in[0];
  const int*   ei  = (const int*)d_in[1];
  const float* Wl0 = (const float*)d_in[2];
  const float* Wr0 = (const float*)d_in[3];
  const float* b0  = (const float*)d_in[4];
  const float* Wl1 = (const float*)d_in[5];
  const float* Wr1 = (const float*)d_in[6];
  const float* b1  = (const float*)d_in[7];
  const float* Wl2 = (const float*)d_in[8];
  const float* Wr2 = (const float*)d_in[9];
  const float* b2  = (const float*)d_in[10];
  float* out = (float*)d_out;

  const int N = in_sizes[0] / 64;   // 100000
  const int E = in_sizes[1] / 2;    // 1600000
  const int* srcv = ei;
  const int* dstv = ei + E;
  const int NB = (N + BW - 1) >> LOGBW;   // 782

  auto al = [](size_t v) { return (v + 255) & ~(size_t)255; };
  char* w = (char*)d_ws;
  size_t oBcur = 0;
  size_t oRow  = oBcur + al(4 * (size_t)NB);
  size_t oDeg  = oRow + al(4 * (size_t)N);
  size_t oDinv = oDeg + al(4 * (size_t)N);
  size_t oBin  = oDinv + al(4 * (size_t)N);
  size_t oCol  = oBin + al(4 * (size_t)NB * CAPB);
  size_t oP    = oCol + al(4 * (size_t)NB * CAPB);
  size_t oQ    = oP + al(2 * (size_t)N * 64);   // P is bf16
  // total = oQ + 4*N*64  (~56 MiB)

  int*            bcur     = (int*)(w + oBcur);
  int*            rowstart = (int*)(w + oRow);
  int*            degarr   = (int*)(w + oDeg);
  float*          deg_inv  = (float*)(w + oDinv);
  unsigned*       binned   = (unsigned*)(w + oBin);
  int*            colidx   = (int*)(w + oCol);
  unsigned short* P        = (unsigned short*)(w + oP);   // bf16 t buffer
  float*          Q        = (float*)(w + oQ);

  hipMemsetAsync(bcur, 0, (size_t)NB * 4, stream);

  int bbl = (E + 2047) / 2048;   // 782
  bucket_bin<<<bbl, 256, 0, stream>>>(srcv, dstv, bcur, binned, NB, E);
  bucket_csr<<<NB, 256, 0, stream>>>(binned, bcur, rowstart, degarr, deg_inv, colidx, N);

  int gb = (N + 63) / 64;
  gemm_dual<64><<<gb, 256, 0, stream>>>(x, Wl0, Wr0, b0, P, Q, N);
  gather_mean<64, true><<<(N + 15) / 16, 256, 0, stream>>>((const uint2*)P, Q, deg_inv, rowstart, degarr, colidx, Q, N);
  gemm_dual<64><<<gb, 256, 0, stream>>>(Q, Wl1, Wr1, b1, P, Q, N);
  gather_mean<64, true><<<(N + 15) / 16, 256, 0, stream>>>((const uint2*)P, Q, deg_inv, rowstart, degarr, colidx, Q, N);
  gemm_dual<32><<<gb, 128, 0, stream>>>(Q, Wl2, Wr2, b2, P, out, N);
  gather_mean<32, false><<<(N + 31) / 32, 256, 0, stream>>>((const uint2*)P, out, deg_inv, rowstart, degarr, colidx, out, N);
}

// Round 7
// 319.143 us; speedup vs baseline: 4.9629x; 1.0152x over previous
//
#include <hip/hip_runtime.h>
#include <cstdint>
#include <cstddef>

// GraphSAGE 3-layer, N=100000 nodes, E=1600000 edges, dims 64->64->64->32.
// Transform-then-aggregate; padded CSR built in 2 kernels via 256-node
// super-buckets (coarse bin -> per-super count/scan/sort, all L2-local);
// gather reads bf16-packed transformed features (uint2 per lane, 16
// lanes/node, 8-edge unroll), accumulates fp32.
// R4 post-mortem: LDS-atomic aggregation (ds_add_f32) is 12x slower than the
// CSR gather — do not revisit.
// R6 post-mortem: fine-bucket (128-node) direct binning scatters ~2.6 words
// per 10KB region -> 43MB WRITE for 6.4MB logical; fix is run length /
// L2 residency (this round), not grid shape.

constexpr int SBW = 256;     // dst nodes per super-bucket
constexpr int LOGSBW = 8;
constexpr int CAPS = 4608;   // super capacity; mean 4096, sigma ~64 (+8σ)
// NSB = ceil(N/256) = 391 for N=100000 (hist array supports NSB <= 512)

__device__ inline unsigned short f2bf(float f) {
  unsigned u = __builtin_bit_cast(unsigned, f);
  u += 0x7FFFu + ((u >> 16) & 1u);          // round-to-nearest-even
  return (unsigned short)(u >> 16);
}
__device__ inline float bf2f(unsigned short b) {
  unsigned u = ((unsigned)b) << 16;
  return __builtin_bit_cast(float, u);
}

// ---------------- pass 1: coarse bin into 256-node super-buckets ----------
// 8192-edge chunks (196 blocks). LDS hist over supers, one global atomic per
// touched super to reserve a run (~21 words -> line-dense), scatter packed
// (src | dstlocal<<17). bcur ends holding exact per-super edge counts.

__global__ __launch_bounds__(256) void bin_coarse(const int* __restrict__ src,
                                                  const int* __restrict__ dst,
                                                  int* __restrict__ bcur,
                                                  unsigned int* __restrict__ coarse,
                                                  int NSB, int E) {
  __shared__ int h[512];
  for (int i = threadIdx.x; i < NSB; i += 256) h[i] = 0;
  __syncthreads();
  int e0 = blockIdx.x * 8192;
  int e1 = min(E, e0 + 8192);
  for (int e = e0 + (int)threadIdx.x; e < e1; e += 256)
    atomicAdd(&h[dst[e] >> LOGSBW], 1);
  __syncthreads();
  for (int i = threadIdx.x; i < NSB; i += 256) {
    int c = h[i];
    h[i] = c ? (i * CAPS + atomicAdd(&bcur[i], c)) : 0;  // slot -> abs cursor
  }
  __syncthreads();
  for (int e = e0 + (int)threadIdx.x; e < e1; e += 256) {
    int d = dst[e];
    int b = d >> LOGSBW;
    int pos = atomicAdd(&h[b], 1);
    if (pos < (b + 1) * CAPS)                 // overflow guard (never taken)
      coarse[pos] = (unsigned)src[e] | ((unsigned)(d & (SBW - 1)) << 17);
  }
}

// ---------------- pass 2: per-super count/scan/sort -> padded CSR ---------
// One block (256 thr) per super; thread tid owns node tid. All colidx writes
// land in the super's contiguous ~18KB span (L2-resident, full lines).

__global__ __launch_bounds__(256) void super_csr(const unsigned int* __restrict__ coarse,
                                                 const int* __restrict__ bcur,
                                                 int* __restrict__ rowstart,
                                                 int* __restrict__ degarr,
                                                 float* __restrict__ deg_inv,
                                                 int* __restrict__ colidx,
                                                 int N) {
  __shared__ int cnt[SBW];
  __shared__ int sc[SBW];
  __shared__ int cur[SBW];
  const int b = blockIdx.x;
  const int tid = threadIdx.x;
  cnt[tid] = 0;
  __syncthreads();
  const int ec = min(bcur[b], CAPS);
  const int base = b * CAPS;
  for (int e = tid; e < ec; e += 256)
    atomicAdd(&cnt[coarse[base + e] >> 17], 1);
  __syncthreads();
  int v = cnt[tid];
  sc[tid] = v;
  __syncthreads();
  for (int off = 1; off < SBW; off <<= 1) {
    int y = sc[tid];
    if (tid >= off) y += sc[tid - off];
    __syncthreads();
    sc[tid] = y;
    __syncthreads();
  }
  int ex = sc[tid] - v;                       // exclusive prefix
  cur[tid] = ex;
  int gn = b * SBW + tid;
  if (gn < N) {
    rowstart[gn] = base + ex;
    degarr[gn] = v;
    deg_inv[gn] = 1.0f / (float)(v > 1 ? v : 1);
  }
  __syncthreads();
  for (int e = tid; e < ec; e += 256) {
    unsigned p = coarse[base + e];
    int dl = (int)(p >> 17);
    int s = (int)(p & 0x1FFFFu);
    int l = atomicAdd(&cur[dl], 1);
    colidx[base + l] = s;
  }
}

// ---------------- fused dual GEMM: t = bf16(h@Wl) ; r = h@Wr + b ----------
// K = 64 fixed. Block: 64-row tile, thread tile 4 rows x 8 cols (4 t + 4 r).
// h and r_out may alias in-place — no __restrict__ on those two.

template <int DOUT>
__global__ __launch_bounds__(256) void gemm_dual(const float* h,
                                                 const float* __restrict__ Wl,
                                                 const float* __restrict__ Wr,
                                                 const float* __restrict__ bias,
                                                 unsigned short* __restrict__ t_out,
                                                 float* r_out, int N) {
  constexpr int TC = 2 * DOUT;
  constexpr int NC = TC / 8;
  constexpr int NT = 16 * NC;
  __shared__ float hs[64 * 68];
  __shared__ float wsh[64 * TC];

  const int tid = threadIdx.x;
  const int row0 = blockIdx.x * 64;

  for (int idx = tid; idx < 64 * 16; idx += NT) {
    int r = idx >> 4, c4 = (idx & 15) << 2;
    int gr = row0 + r;
    if (gr > N - 1) gr = N - 1;
    float4 v = *(const float4*)&h[(size_t)gr * 64 + c4];
    *(float4*)&hs[r * 68 + c4] = v;
  }
  for (int idx = tid; idx < 16 * DOUT; idx += NT) {
    int f = idx << 2;
    int k = f / DOUT, c = f % DOUT;
    *(float4*)&wsh[k * TC + c] = *(const float4*)&Wl[f];
    *(float4*)&wsh[k * TC + DOUT + c] = *(const float4*)&Wr[f];
  }
  __syncthreads();

  const int cid = tid % NC;
  const int rid = tid / NC;
  float acc[4][8];
#pragma unroll
  for (int i = 0; i < 4; ++i)
#pragma unroll
    for (int m = 0; m < 8; ++m) acc[i][m] = 0.f;

#pragma unroll 8
  for (int k = 0; k < 64; ++k) {
    float4 w0 = *(const float4*)&wsh[k * TC + 4 * cid];
    float4 w1 = *(const float4*)&wsh[k * TC + DOUT + 4 * cid];
#pragma unroll
    for (int i = 0; i < 4; ++i) {
      float hv = hs[(4 * rid + i) * 68 + k];
      acc[i][0] += hv * w0.x; acc[i][1] += hv * w0.y;
      acc[i][2] += hv * w0.z; acc[i][3] += hv * w0.w;
      acc[i][4] += hv * w1.x; acc[i][5] += hv * w1.y;
      acc[i][6] += hv * w1.z; acc[i][7] += hv * w1.w;
    }
  }

  float4 bv = *(const float4*)&bias[4 * cid];
#pragma unroll
  for (int i = 0; i < 4; ++i) {
    int gr = row0 + 4 * rid + i;
    if (gr < N) {
      ushort4 tv;
      tv.x = f2bf(acc[i][0]); tv.y = f2bf(acc[i][1]);
      tv.z = f2bf(acc[i][2]); tv.w = f2bf(acc[i][3]);
      *(ushort4*)&t_out[(size_t)gr * DOUT + 4 * cid] = tv;
      *(float4*)&r_out[(size_t)gr * DOUT + 4 * cid] =
          make_float4(acc[i][4] + bv.x, acc[i][5] + bv.y,
                      acc[i][6] + bv.z, acc[i][7] + bv.w);
    }
  }
}

// ------ gather: out = elu?(deg_inv * sum t[src] + r[dst]), t is bf16 ------
// DOUT/4 lanes per node; each lane owns 4 features via one uint2 (8 B) load
// per edge — a 64-lane wave serves 4 nodes, 8-edge unroll => up to 32 row
// loads in flight per wave. r and out alias in place; no restrict there.

template <int DOUT, bool DO_ELU>
__global__ __launch_bounds__(256) void gather_mean(const uint2* __restrict__ t,
                                                   const float* r,
                                                   const float* __restrict__ deg_inv,
                                                   const int* __restrict__ rowstart,
                                                   const int* __restrict__ degarr,
                                                   const int* __restrict__ colidx,
                                                   float* out, int N) {
  constexpr int L = DOUT / 4;                 // uint2 lanes per node: 16 or 8
  int node = blockIdx.x * (256 / L) + threadIdx.x / L;
  int lane = threadIdx.x & (L - 1);
  if (node >= N) return;
  int b = rowstart[node];
  int e = b + degarr[node];
  float s0 = 0.f, s1 = 0.f, s2 = 0.f, s3 = 0.f;
  int i = b;
  for (; i + 8 <= e; i += 8) {
    uint2 v[8];
#pragma unroll
    for (int j = 0; j < 8; ++j)
      v[j] = t[(size_t)colidx[i + j] * L + lane];
#pragma unroll
    for (int j = 0; j < 8; ++j) {
      s0 += bf2f((unsigned short)(v[j].x & 0xFFFFu));
      s1 += bf2f((unsigned short)(v[j].x >> 16));
      s2 += bf2f((unsigned short)(v[j].y & 0xFFFFu));
      s3 += bf2f((unsigned short)(v[j].y >> 16));
    }
  }
  for (; i < e; ++i) {
    uint2 v = t[(size_t)colidx[i] * L + lane];
    s0 += bf2f((unsigned short)(v.x & 0xFFFFu));
    s1 += bf2f((unsigned short)(v.x >> 16));
    s2 += bf2f((unsigned short)(v.y & 0xFFFFu));
    s3 += bf2f((unsigned short)(v.y >> 16));
  }
  float dv = deg_inv[node];
  float4 rv = *(const float4*)&r[(size_t)node * DOUT + 4 * lane];
  float a0 = s0 * dv + rv.x;
  float a1 = s1 * dv + rv.y;
  float a2 = s2 * dv + rv.z;
  float a3 = s3 * dv + rv.w;
  if (DO_ELU) {
    a0 = a0 > 0.f ? a0 : (expf(a0) - 1.f);
    a1 = a1 > 0.f ? a1 : (expf(a1) - 1.f);
    a2 = a2 > 0.f ? a2 : (expf(a2) - 1.f);
    a3 = a3 > 0.f ? a3 : (expf(a3) - 1.f);
  }
  *(float4*)&out[(size_t)node * DOUT + 4 * lane] = make_float4(a0, a1, a2, a3);
}

// ---------------- launch ----------------

extern "C" void kernel_launch(void* const* d_in, const int* in_sizes, int n_in,
                              void* d_out, int out_size, void* d_ws, size_t ws_size,
                              hipStream_t stream) {
  const float* x   = (const float*)d_in[0];
  const int*   ei  = (const int*)d_in[1];
  const float* Wl0 = (const float*)d_in[2];
  const float* Wr0 = (const float*)d_in[3];
  const float* b0  = (const float*)d_in[4];
  const float* Wl1 = (const float*)d_in[5];
  const float* Wr1 = (const float*)d_in[6];
  const float* b1  = (const float*)d_in[7];
  const float* Wl2 = (const float*)d_in[8];
  const float* Wr2 = (const float*)d_in[9];
  const float* b2  = (const float*)d_in[10];
  float* out = (float*)d_out;

  const int N = in_sizes[0] / 64;   // 100000
  const int E = in_sizes[1] / 2;    // 1600000
  const int* srcv = ei;
  const int* dstv = ei + E;
  const int NSB = (N + SBW - 1) >> LOGSBW;   // 391

  auto al = [](size_t v) { return (v + 255) & ~(size_t)255; };
  char* w = (char*)d_ws;
  size_t oBcur = 0;
  size_t oRow  = oBcur + al(4 * (size_t)NSB);
  size_t oDeg  = oRow + al(4 * (size_t)N);
  size_t oDinv = oDeg + al(4 * (size_t)N);
  size_t oBin  = oDinv + al(4 * (size_t)N);
  size_t oCol  = oBin + al(4 * (size_t)NSB * CAPS);
  size_t oP    = oCol + al(4 * (size_t)NSB * CAPS);
  size_t oQ    = oP + al(2 * (size_t)N * 64);   // P is bf16
  // total = oQ + 4*N*64  (~55 MiB)

  int*            bcur     = (int*)(w + oBcur);
  int*            rowstart = (int*)(w + oRow);
  int*            degarr   = (int*)(w + oDeg);
  float*          deg_inv  = (float*)(w + oDinv);
  unsigned*       coarse   = (unsigned*)(w + oBin);
  int*            colidx   = (int*)(w + oCol);
  unsigned short* P        = (unsigned short*)(w + oP);   // bf16 t buffer
  float*          Q        = (float*)(w + oQ);

  hipMemsetAsync(bcur, 0, (size_t)NSB * 4, stream);

  int bbl = (E + 8191) / 8192;   // 196
  bin_coarse<<<bbl, 256, 0, stream>>>(srcv, dstv, bcur, coarse, NSB, E);
  super_csr<<<NSB, 256, 0, stream>>>(coarse, bcur, rowstart, degarr, deg_inv, colidx, N);

  int gb = (N + 63) / 64;
  gemm_dual<64><<<gb, 256, 0, stream>>>(x, Wl0, Wr0, b0, P, Q, N);
  gather_mean<64, true><<<(N + 15) / 16, 256, 0, stream>>>((const uint2*)P, Q, deg_inv, rowstart, degarr, colidx, Q, N);
  gemm_dual<64><<<gb, 256, 0, stream>>>(Q, Wl1, Wr1, b1, P, Q, N);
  gather_mean<64, true><<<(N + 15) / 16, 256, 0, stream>>>((const uint2*)P, Q, deg_inv, rowstart, degarr, colidx, Q, N);
  gemm_dual<32><<<gb, 128, 0, stream>>>(Q, Wl2, Wr2, b2, P, out, N);
  gather_mean<32, false><<<(N + 31) / 32, 256, 0, stream>>>((const uint2*)P, out, deg_inv, rowstart, degarr, colidx, out, N);
}

// Round 8
// 317.228 us; speedup vs baseline: 4.9929x; 1.0060x over previous
//
#include <hip/hip_runtime.h>
#include <cstdint>
#include <cstddef>

// GraphSAGE 3-layer, N=100000 nodes, E=1600000 edges, dims 64->64->64->32.
// Transform-then-aggregate; padded CSR built in 2 kernels via 256-node
// super-buckets (coarse bin -> per-super count/scan/sort); gather reads
// bf16-packed transformed features (uint2/lane, 16 lanes/node, 8-edge
// unroll), accumulates fp32.
// R4 post-mortem: LDS-atomic aggregation is 12x slower than CSR gather.
// R6 post-mortem: short scatter runs -> 64B-line write amplification.
// R7 post-mortem: 196-block bin_coarse is latency-bound (6.8% occupancy,
// 390 GB/s); fix = LDS-cache the chunk (no global re-read) + 782 blocks.

constexpr int SBW = 256;     // dst nodes per super-bucket
constexpr int LOGSBW = 8;
constexpr int CAPS = 4608;   // super capacity; mean 4096, sigma ~64 (+8σ)
constexpr int CHK = 2048;    // edges per bin_coarse block -> 782 blocks
// NSB = ceil(N/256) = 391 for N=100000 (hist array supports NSB <= 512)

__device__ inline unsigned short f2bf(float f) {
  unsigned u = __builtin_bit_cast(unsigned, f);
  u += 0x7FFFu + ((u >> 16) & 1u);          // round-to-nearest-even
  return (unsigned short)(u >> 16);
}
__device__ inline float bf2f(unsigned short b) {
  unsigned u = ((unsigned)b) << 16;
  return __builtin_bit_cast(float, u);
}

// ---------------- pass 1: coarse bin into 256-node super-buckets ----------
// 2048-edge chunks (782 blocks, ~12 waves/CU). One global pass: load
// (src,dst), pack (src | dl<<17) + super id into LDS, LDS histogram.
// Then per-super range reservation (1 global atomic each) and scatter
// straight from LDS. bcur ends holding exact per-super edge counts.

__global__ __launch_bounds__(256) void bin_coarse(const int* __restrict__ src,
                                                  const int* __restrict__ dst,
                                                  int* __restrict__ bcur,
                                                  unsigned int* __restrict__ coarse,
                                                  int NSB, int E) {
  __shared__ int h[512];
  __shared__ unsigned ed[CHK];
  __shared__ short sb[CHK];
  const int tid = threadIdx.x;
  for (int i = tid; i < NSB; i += 256) h[i] = 0;
  __syncthreads();
  const int e0 = blockIdx.x * CHK;
  const int e1 = min(E, e0 + CHK);
  for (int e = e0 + tid; e < e1; e += 256) {
    int d = dst[e];
    int s = src[e];
    int b = d >> LOGSBW;
    ed[e - e0] = (unsigned)s | ((unsigned)(d & (SBW - 1)) << 17);
    sb[e - e0] = (short)b;
    atomicAdd(&h[b], 1);
  }
  __syncthreads();
  for (int i = tid; i < NSB; i += 256) {
    int c = h[i];
    h[i] = c ? (i * CAPS + atomicAdd(&bcur[i], c)) : 0;  // slot -> abs cursor
  }
  __syncthreads();
  const int n = e1 - e0;
  for (int k = tid; k < n; k += 256) {
    int b = sb[k];
    int pos = atomicAdd(&h[b], 1);
    if (pos < (b + 1) * CAPS)                 // overflow guard (never taken)
      coarse[pos] = ed[k];
  }
}

// ---------------- pass 2: per-super count/scan/sort -> padded CSR ---------
// One block (256 thr) per super; thread tid owns node tid. All colidx writes
// land in the super's contiguous ~18KB span (L2-resident, full lines).

__global__ __launch_bounds__(256) void super_csr(const unsigned int* __restrict__ coarse,
                                                 const int* __restrict__ bcur,
                                                 int* __restrict__ rowstart,
                                                 int* __restrict__ degarr,
                                                 float* __restrict__ deg_inv,
                                                 int* __restrict__ colidx,
                                                 int N) {
  __shared__ int cnt[SBW];
  __shared__ int sc[SBW];
  __shared__ int cur[SBW];
  const int b = blockIdx.x;
  const int tid = threadIdx.x;
  cnt[tid] = 0;
  __syncthreads();
  const int ec = min(bcur[b], CAPS);
  const int base = b * CAPS;
  for (int e = tid; e < ec; e += 256)
    atomicAdd(&cnt[coarse[base + e] >> 17], 1);
  __syncthreads();
  int v = cnt[tid];
  sc[tid] = v;
  __syncthreads();
  for (int off = 1; off < SBW; off <<= 1) {
    int y = sc[tid];
    if (tid >= off) y += sc[tid - off];
    __syncthreads();
    sc[tid] = y;
    __syncthreads();
  }
  int ex = sc[tid] - v;                       // exclusive prefix
  cur[tid] = ex;
  int gn = b * SBW + tid;
  if (gn < N) {
    rowstart[gn] = base + ex;
    degarr[gn] = v;
    deg_inv[gn] = 1.0f / (float)(v > 1 ? v : 1);
  }
  __syncthreads();
  for (int e = tid; e < ec; e += 256) {
    unsigned p = coarse[base + e];
    int dl = (int)(p >> 17);
    int s = (int)(p & 0x1FFFFu);
    int l = atomicAdd(&cur[dl], 1);
    colidx[base + l] = s;
  }
}

// ---------------- fused dual GEMM: t = bf16(h@Wl) ; r = h@Wr + b ----------
// K = 64 fixed. Block: 64-row tile, thread tile 4 rows x 8 cols (4 t + 4 r).
// h and r_out may alias in-place — no __restrict__ on those two.

template <int DOUT>
__global__ __launch_bounds__(256) void gemm_dual(const float* h,
                                                 const float* __restrict__ Wl,
                                                 const float* __restrict__ Wr,
                                                 const float* __restrict__ bias,
                                                 unsigned short* __restrict__ t_out,
                                                 float* r_out, int N) {
  constexpr int TC = 2 * DOUT;
  constexpr int NC = TC / 8;
  constexpr int NT = 16 * NC;
  __shared__ float hs[64 * 68];
  __shared__ float wsh[64 * TC];

  const int tid = threadIdx.x;
  const int row0 = blockIdx.x * 64;

  for (int idx = tid; idx < 64 * 16; idx += NT) {
    int r = idx >> 4, c4 = (idx & 15) << 2;
    int gr = row0 + r;
    if (gr > N - 1) gr = N - 1;
    float4 v = *(const float4*)&h[(size_t)gr * 64 + c4];
    *(float4*)&hs[r * 68 + c4] = v;
  }
  for (int idx = tid; idx < 16 * DOUT; idx += NT) {
    int f = idx << 2;
    int k = f / DOUT, c = f % DOUT;
    *(float4*)&wsh[k * TC + c] = *(const float4*)&Wl[f];
    *(float4*)&wsh[k * TC + DOUT + c] = *(const float4*)&Wr[f];
  }
  __syncthreads();

  const int cid = tid % NC;
  const int rid = tid / NC;
  float acc[4][8];
#pragma unroll
  for (int i = 0; i < 4; ++i)
#pragma unroll
    for (int m = 0; m < 8; ++m) acc[i][m] = 0.f;

#pragma unroll 8
  for (int k = 0; k < 64; ++k) {
    float4 w0 = *(const float4*)&wsh[k * TC + 4 * cid];
    float4 w1 = *(const float4*)&wsh[k * TC + DOUT + 4 * cid];
#pragma unroll
    for (int i = 0; i < 4; ++i) {
      float hv = hs[(4 * rid + i) * 68 + k];
      acc[i][0] += hv * w0.x; acc[i][1] += hv * w0.y;
      acc[i][2] += hv * w0.z; acc[i][3] += hv * w0.w;
      acc[i][4] += hv * w1.x; acc[i][5] += hv * w1.y;
      acc[i][6] += hv * w1.z; acc[i][7] += hv * w1.w;
    }
  }

  float4 bv = *(const float4*)&bias[4 * cid];
#pragma unroll
  for (int i = 0; i < 4; ++i) {
    int gr = row0 + 4 * rid + i;
    if (gr < N) {
      ushort4 tv;
      tv.x = f2bf(acc[i][0]); tv.y = f2bf(acc[i][1]);
      tv.z = f2bf(acc[i][2]); tv.w = f2bf(acc[i][3]);
      *(ushort4*)&t_out[(size_t)gr * DOUT + 4 * cid] = tv;
      *(float4*)&r_out[(size_t)gr * DOUT + 4 * cid] =
          make_float4(acc[i][4] + bv.x, acc[i][5] + bv.y,
                      acc[i][6] + bv.z, acc[i][7] + bv.w);
    }
  }
}

// ------ gather: out = elu?(deg_inv * sum t[src] + r[dst]), t is bf16 ------
// DOUT/4 lanes per node; each lane owns 4 features via one uint2 (8 B) load
// per edge — a 64-lane wave serves 4 nodes, 8-edge unroll => up to 32 row
// loads in flight per wave. r and out alias in place; no restrict there.

template <int DOUT, bool DO_ELU>
__global__ __launch_bounds__(256) void gather_mean(const uint2* __restrict__ t,
                                                   const float* r,
                                                   const float* __restrict__ deg_inv,
                                                   const int* __restrict__ rowstart,
                                                   const int* __restrict__ degarr,
                                                   const int* __restrict__ colidx,
                                                   float* out, int N) {
  constexpr int L = DOUT / 4;                 // uint2 lanes per node: 16 or 8
  int node = blockIdx.x * (256 / L) + threadIdx.x / L;
  int lane = threadIdx.x & (L - 1);
  if (node >= N) return;
  int b = rowstart[node];
  int e = b + degarr[node];
  float s0 = 0.f, s1 = 0.f, s2 = 0.f, s3 = 0.f;
  int i = b;
  for (; i + 8 <= e; i += 8) {
    uint2 v[8];
#pragma unroll
    for (int j = 0; j < 8; ++j)
      v[j] = t[(size_t)colidx[i + j] * L + lane];
#pragma unroll
    for (int j = 0; j < 8; ++j) {
      s0 += bf2f((unsigned short)(v[j].x & 0xFFFFu));
      s1 += bf2f((unsigned short)(v[j].x >> 16));
      s2 += bf2f((unsigned short)(v[j].y & 0xFFFFu));
      s3 += bf2f((unsigned short)(v[j].y >> 16));
    }
  }
  for (; i < e; ++i) {
    uint2 v = t[(size_t)colidx[i] * L + lane];
    s0 += bf2f((unsigned short)(v.x & 0xFFFFu));
    s1 += bf2f((unsigned short)(v.x >> 16));
    s2 += bf2f((unsigned short)(v.y & 0xFFFFu));
    s3 += bf2f((unsigned short)(v.y >> 16));
  }
  float dv = deg_inv[node];
  float4 rv = *(const float4*)&r[(size_t)node * DOUT + 4 * lane];
  float a0 = s0 * dv + rv.x;
  float a1 = s1 * dv + rv.y;
  float a2 = s2 * dv + rv.z;
  float a3 = s3 * dv + rv.w;
  if (DO_ELU) {
    a0 = a0 > 0.f ? a0 : (expf(a0) - 1.f);
    a1 = a1 > 0.f ? a1 : (expf(a1) - 1.f);
    a2 = a2 > 0.f ? a2 : (expf(a2) - 1.f);
    a3 = a3 > 0.f ? a3 : (expf(a3) - 1.f);
  }
  *(float4*)&out[(size_t)node * DOUT + 4 * lane] = make_float4(a0, a1, a2, a3);
}

// ---------------- launch ----------------

extern "C" void kernel_launch(void* const* d_in, const int* in_sizes, int n_in,
                              void* d_out, int out_size, void* d_ws, size_t ws_size,
                              hipStream_t stream) {
  const float* x   = (const float*)d_in[0];
  const int*   ei  = (const int*)d_in[1];
  const float* Wl0 = (const float*)d_in[2];
  const float* Wr0 = (const float*)d_in[3];
  const float* b0  = (const float*)d_in[4];
  const float* Wl1 = (const float*)d_in[5];
  const float* Wr1 = (const float*)d_in[6];
  const float* b1  = (const float*)d_in[7];
  const float* Wl2 = (const float*)d_in[8];
  const float* Wr2 = (const float*)d_in[9];
  const float* b2  = (const float*)d_in[10];
  float* out = (float*)d_out;

  const int N = in_sizes[0] / 64;   // 100000
  const int E = in_sizes[1] / 2;    // 1600000
  const int* srcv = ei;
  const int* dstv = ei + E;
  const int NSB = (N + SBW - 1) >> LOGSBW;   // 391

  auto al = [](size_t v) { return (v + 255) & ~(size_t)255; };
  char* w = (char*)d_ws;
  size_t oBcur = 0;
  size_t oRow  = oBcur + al(4 * (size_t)NSB);
  size_t oDeg  = oRow + al(4 * (size_t)N);
  size_t oDinv = oDeg + al(4 * (size_t)N);
  size_t oBin  = oDinv + al(4 * (size_t)N);
  size_t oCol  = oBin + al(4 * (size_t)NSB * CAPS);
  size_t oP    = oCol + al(4 * (size_t)NSB * CAPS);
  size_t oQ    = oP + al(2 * (size_t)N * 64);   // P is bf16
  // total = oQ + 4*N*64  (~55 MiB)

  int*            bcur     = (int*)(w + oBcur);
  int*            rowstart = (int*)(w + oRow);
  int*            degarr   = (int*)(w + oDeg);
  float*          deg_inv  = (float*)(w + oDinv);
  unsigned*       coarse   = (unsigned*)(w + oBin);
  int*            colidx   = (int*)(w + oCol);
  unsigned short* P        = (unsigned short*)(w + oP);   // bf16 t buffer
  float*          Q        = (float*)(w + oQ);

  hipMemsetAsync(bcur, 0, (size_t)NSB * 4, stream);

  int bbl = (E + CHK - 1) / CHK;   // 782
  bin_coarse<<<bbl, 256, 0, stream>>>(srcv, dstv, bcur, coarse, NSB, E);
  super_csr<<<NSB, 256, 0, stream>>>(coarse, bcur, rowstart, degarr, deg_inv, colidx, N);

  int gb = (N + 63) / 64;
  gemm_dual<64><<<gb, 256, 0, stream>>>(x, Wl0, Wr0, b0, P, Q, N);
  gather_mean<64, true><<<(N + 15) / 16, 256, 0, stream>>>((const uint2*)P, Q, deg_inv, rowstart, degarr, colidx, Q, N);
  gemm_dual<64><<<gb, 256, 0, stream>>>(Q, Wl1, Wr1, b1, P, Q, N);
  gather_mean<64, true><<<(N + 15) / 16, 256, 0, stream>>>((const uint2*)P, Q, deg_inv, rowstart, degarr, colidx, Q, N);
  gemm_dual<32><<<gb, 128, 0, stream>>>(Q, Wl2, Wr2, b2, P, out, N);
  gather_mean<32, false><<<(N + 31) / 32, 256, 0, stream>>>((const uint2*)P, out, deg_inv, rowstart, degarr, colidx, out, N);
}

// Round 9
// 283.440 us; speedup vs baseline: 5.5881x; 1.1192x over previous
//
#include <hip/hip_runtime.h>
#include <cstdint>
#include <cstddef>

// GraphSAGE 3-layer, N=100000 nodes, E=1600000 edges, dims 64->64->64->32.
// Transform-then-aggregate; padded CSR via 256-node super-buckets (2 kernels);
// inter-layer features kept in bf16; per-layer dual GEMM (t=h@Wl bf16 out,
// r=h@Wr+b fp32 out) done with mfma_f32_16x16x32_bf16, LDS-free A-path;
// gather reads bf16 t rows (uint2/lane, 16 lanes/node, 8-edge unroll),
// accumulates fp32.
// R4 post-mortem: LDS-atomic aggregation is 12x slower than CSR gather.
// R6 post-mortem: short scatter runs -> 64B-line write amplification.
// R7 post-mortem: 196-block bin_coarse latency-bound; LDS-cache + 782 blocks.
// R8: GEMMs moved to MFMA (fp32 VALU was ~2cy/fmac bound); h stored bf16.

constexpr int SBW = 256;     // dst nodes per super-bucket
constexpr int LOGSBW = 8;
constexpr int CAPS = 4608;   // super capacity; mean 4096, sigma ~64 (+8σ)
constexpr int CHK = 2048;    // edges per bin_coarse block -> 782 blocks

typedef __attribute__((ext_vector_type(8))) short s16x8;
typedef __attribute__((ext_vector_type(4))) float f32x4;

__device__ inline unsigned short f2bf(float f) {
  unsigned u = __builtin_bit_cast(unsigned, f);
  u += 0x7FFFu + ((u >> 16) & 1u);          // round-to-nearest-even
  return (unsigned short)(u >> 16);
}
__device__ inline float bf2f(unsigned short b) {
  unsigned u = ((unsigned)b) << 16;
  return __builtin_bit_cast(float, u);
}

// ---------------- pass 1: coarse bin into 256-node super-buckets ----------

__global__ __launch_bounds__(256) void bin_coarse(const int* __restrict__ src,
                                                  const int* __restrict__ dst,
                                                  int* __restrict__ bcur,
                                                  unsigned int* __restrict__ coarse,
                                                  int NSB, int E) {
  __shared__ int h[512];
  __shared__ unsigned ed[CHK];
  __shared__ short sb[CHK];
  const int tid = threadIdx.x;
  for (int i = tid; i < NSB; i += 256) h[i] = 0;
  __syncthreads();
  const int e0 = blockIdx.x * CHK;
  const int e1 = min(E, e0 + CHK);
  for (int e = e0 + tid; e < e1; e += 256) {
    int d = dst[e];
    int s = src[e];
    int b = d >> LOGSBW;
    ed[e - e0] = (unsigned)s | ((unsigned)(d & (SBW - 1)) << 17);
    sb[e - e0] = (short)b;
    atomicAdd(&h[b], 1);
  }
  __syncthreads();
  for (int i = tid; i < NSB; i += 256) {
    int c = h[i];
    h[i] = c ? (i * CAPS + atomicAdd(&bcur[i], c)) : 0;  // slot -> abs cursor
  }
  __syncthreads();
  const int n = e1 - e0;
  for (int k = tid; k < n; k += 256) {
    int b = sb[k];
    int pos = atomicAdd(&h[b], 1);
    if (pos < (b + 1) * CAPS)                 // overflow guard (never taken)
      coarse[pos] = ed[k];
  }
}

// ---------------- pass 2: per-super count/scan/sort -> padded CSR ---------

__global__ __launch_bounds__(256) void super_csr(const unsigned int* __restrict__ coarse,
                                                 const int* __restrict__ bcur,
                                                 int* __restrict__ rowstart,
                                                 int* __restrict__ degarr,
                                                 float* __restrict__ deg_inv,
                                                 int* __restrict__ colidx,
                                                 int N) {
  __shared__ int cnt[SBW];
  __shared__ int sc[SBW];
  __shared__ int cur[SBW];
  const int b = blockIdx.x;
  const int tid = threadIdx.x;
  cnt[tid] = 0;
  __syncthreads();
  const int ec = min(bcur[b], CAPS);
  const int base = b * CAPS;
  for (int e = tid; e < ec; e += 256)
    atomicAdd(&cnt[coarse[base + e] >> 17], 1);
  __syncthreads();
  int v = cnt[tid];
  sc[tid] = v;
  __syncthreads();
  for (int off = 1; off < SBW; off <<= 1) {
    int y = sc[tid];
    if (tid >= off) y += sc[tid - off];
    __syncthreads();
    sc[tid] = y;
    __syncthreads();
  }
  int ex = sc[tid] - v;                       // exclusive prefix
  cur[tid] = ex;
  int gn = b * SBW + tid;
  if (gn < N) {
    rowstart[gn] = base + ex;
    degarr[gn] = v;
    deg_inv[gn] = 1.0f / (float)(v > 1 ? v : 1);
  }
  __syncthreads();
  for (int e = tid; e < ec; e += 256) {
    unsigned p = coarse[base + e];
    int dl = (int)(p >> 17);
    int s = (int)(p & 0x1FFFFu);
    int l = atomicAdd(&cur[dl], 1);
    colidx[base + l] = s;
  }
}

// ---------------- fp32 -> bf16 convert (x only, once) ---------------------

__global__ __launch_bounds__(256) void cvt_bf16(const float* __restrict__ x,
                                                unsigned short* __restrict__ y,
                                                int n) {
  int i = (blockIdx.x * 256 + threadIdx.x) * 4;
  if (i < n) {
    float4 v = *(const float4*)&x[i];
    ushort4 o;
    o.x = f2bf(v.x); o.y = f2bf(v.y); o.z = f2bf(v.z); o.w = f2bf(v.w);
    *(ushort4*)&y[i] = o;
  }
}

// ---------------- MFMA dual GEMM: t = bf16(h@Wl) ; r = h@Wr + b -----------
// h is bf16 row-major [N][64]. Block = 4 waves x 16 rows = 64 rows.
// A-frags straight from global (16 full 64B lines per frag-load — line-
// efficient); Wl|Wr staged transposed in LDS as bf16 (144B stride -> 2-way
// banks, free). C/D layout: col=lane&15, row=(lane>>4)*4+reg (m89-verified).

template <int DOUT>
__global__ __launch_bounds__(256) void gemm_mfma(const unsigned short* __restrict__ Hm,
                                                 const float* __restrict__ Wl,
                                                 const float* __restrict__ Wr,
                                                 const float* __restrict__ bias,
                                                 unsigned short* __restrict__ t_out,
                                                 float* __restrict__ r_out, int N) {
  constexpr int NTT = DOUT / 16;      // t col-tiles per wave: 4 or 2
  constexpr int SK = 72;              // padded k-stride (shorts), 144 B
  __shared__ short Wt[2 * DOUT * SK];

  const int tid = threadIdx.x;
  for (int idx = tid; idx < 64 * DOUT; idx += 256) {
    int k = idx / DOUT, c = idx % DOUT;
    Wt[c * SK + k] = (short)f2bf(Wl[idx]);
    Wt[(c + DOUT) * SK + k] = (short)f2bf(Wr[idx]);
  }
  __syncthreads();

  const int wv = tid >> 6, lane = tid & 63;
  const int q = lane >> 4, m = lane & 15;
  const int row = blockIdx.x * 64 + wv * 16 + m;
  const int rowc = row < N ? row : N - 1;
  const s16x8 a0 = *(const s16x8*)&Hm[(size_t)rowc * 64 + q * 8];
  const s16x8 a1 = *(const s16x8*)&Hm[(size_t)rowc * 64 + 32 + q * 8];

  f32x4 acc[2 * NTT];
#pragma unroll
  for (int c = 0; c < 2 * NTT; ++c) acc[c] = (f32x4){0.f, 0.f, 0.f, 0.f};

#pragma unroll
  for (int c = 0; c < 2 * NTT; ++c) {
    const short* wp = &Wt[(c * 16 + m) * SK];
    s16x8 b0 = *(const s16x8*)&wp[q * 8];
    s16x8 b1 = *(const s16x8*)&wp[32 + q * 8];
    acc[c] = __builtin_amdgcn_mfma_f32_16x16x32_bf16(a0, b0, acc[c], 0, 0, 0);
    acc[c] = __builtin_amdgcn_mfma_f32_16x16x32_bf16(a1, b1, acc[c], 0, 0, 0);
  }

  const int orow = blockIdx.x * 64 + wv * 16 + q * 4;
#pragma unroll
  for (int c = 0; c < NTT; ++c) {
#pragma unroll
    for (int i = 0; i < 4; ++i) {
      int r_ = orow + i;
      if (r_ < N) t_out[(size_t)r_ * DOUT + c * 16 + m] = f2bf(acc[c][i]);
    }
  }
#pragma unroll
  for (int c = 0; c < NTT; ++c) {
    float bv = bias[c * 16 + m];
#pragma unroll
    for (int i = 0; i < 4; ++i) {
      int r_ = orow + i;
      if (r_ < N) r_out[(size_t)r_ * DOUT + c * 16 + m] = acc[NTT + c][i] + bv;
    }
  }
}

// ------ gather: out = elu?(deg_inv * sum t[src] + r[dst]), t is bf16 ------
// DOUT/4 lanes per node; each lane owns 4 features via one uint2 (8 B) load
// per edge; 8-edge unroll => up to 32 row loads in flight per wave.
// BF16OUT: write bf16 h for the next layer's MFMA GEMM (separate buffer, no
// aliasing). Else fp32 out may alias r in place (dependence-ordered).

template <int DOUT, bool DO_ELU, bool BF16OUT>
__global__ __launch_bounds__(256) void gather_mean(const uint2* __restrict__ t,
                                                   const float* r,
                                                   const float* __restrict__ deg_inv,
                                                   const int* __restrict__ rowstart,
                                                   const int* __restrict__ degarr,
                                                   const int* __restrict__ colidx,
                                                   void* out, int N) {
  constexpr int L = DOUT / 4;                 // uint2 lanes per node: 16 or 8
  int node = blockIdx.x * (256 / L) + threadIdx.x / L;
  int lane = threadIdx.x & (L - 1);
  if (node >= N) return;
  int b = rowstart[node];
  int e = b + degarr[node];
  float s0 = 0.f, s1 = 0.f, s2 = 0.f, s3 = 0.f;
  int i = b;
  for (; i + 8 <= e; i += 8) {
    uint2 v[8];
#pragma unroll
    for (int j = 0; j < 8; ++j)
      v[j] = t[(size_t)colidx[i + j] * L + lane];
#pragma unroll
    for (int j = 0; j < 8; ++j) {
      s0 += bf2f((unsigned short)(v[j].x & 0xFFFFu));
      s1 += bf2f((unsigned short)(v[j].x >> 16));
      s2 += bf2f((unsigned short)(v[j].y & 0xFFFFu));
      s3 += bf2f((unsigned short)(v[j].y >> 16));
    }
  }
  for (; i < e; ++i) {
    uint2 v = t[(size_t)colidx[i] * L + lane];
    s0 += bf2f((unsigned short)(v.x & 0xFFFFu));
    s1 += bf2f((unsigned short)(v.x >> 16));
    s2 += bf2f((unsigned short)(v.y & 0xFFFFu));
    s3 += bf2f((unsigned short)(v.y >> 16));
  }
  float dv = deg_inv[node];
  float4 rv = *(const float4*)&r[(size_t)node * DOUT + 4 * lane];
  float a0 = s0 * dv + rv.x;
  float a1 = s1 * dv + rv.y;
  float a2 = s2 * dv + rv.z;
  float a3 = s3 * dv + rv.w;
  if (DO_ELU) {
    a0 = a0 > 0.f ? a0 : (expf(a0) - 1.f);
    a1 = a1 > 0.f ? a1 : (expf(a1) - 1.f);
    a2 = a2 > 0.f ? a2 : (expf(a2) - 1.f);
    a3 = a3 > 0.f ? a3 : (expf(a3) - 1.f);
  }
  if (BF16OUT) {
    ushort4 hv;
    hv.x = f2bf(a0); hv.y = f2bf(a1); hv.z = f2bf(a2); hv.w = f2bf(a3);
    *(ushort4*)&((unsigned short*)out)[(size_t)node * DOUT + 4 * lane] = hv;
  } else {
    *(float4*)&((float*)out)[(size_t)node * DOUT + 4 * lane] =
        make_float4(a0, a1, a2, a3);
  }
}

// ---------------- launch ----------------

extern "C" void kernel_launch(void* const* d_in, const int* in_sizes, int n_in,
                              void* d_out, int out_size, void* d_ws, size_t ws_size,
                              hipStream_t stream) {
  const float* x   = (const float*)d_in[0];
  const int*   ei  = (const int*)d_in[1];
  const float* Wl0 = (const float*)d_in[2];
  const float* Wr0 = (const float*)d_in[3];
  const float* b0  = (const float*)d_in[4];
  const float* Wl1 = (const float*)d_in[5];
  const float* Wr1 = (const float*)d_in[6];
  const float* b1  = (const float*)d_in[7];
  const float* Wl2 = (const float*)d_in[8];
  const float* Wr2 = (const float*)d_in[9];
  const float* b2  = (const float*)d_in[10];
  float* out = (float*)d_out;

  const int N = in_sizes[0] / 64;   // 100000
  const int E = in_sizes[1] / 2;    // 1600000
  const int* srcv = ei;
  const int* dstv = ei + E;
  const int NSB = (N + SBW - 1) >> LOGSBW;   // 391

  auto al = [](size_t v) { return (v + 255) & ~(size_t)255; };
  char* w = (char*)d_ws;
  size_t oBcur = 0;
  size_t oRow  = oBcur + al(4 * (size_t)NSB);
  size_t oDeg  = oRow + al(4 * (size_t)N);
  size_t oDinv = oDeg + al(4 * (size_t)N);
  size_t oBin  = oDinv + al(4 * (size_t)N);
  size_t oCol  = oBin + al(4 * (size_t)NSB * CAPS);
  size_t oP    = oCol + al(4 * (size_t)NSB * CAPS);
  size_t oX    = oP + al(2 * (size_t)N * 64);   // bf16 h buffer
  size_t oR    = oX + al(2 * (size_t)N * 64);   // fp32 r buffer
  // total = oR + 4*N*64  (~67 MiB)

  int*            bcur     = (int*)(w + oBcur);
  int*            rowstart = (int*)(w + oRow);
  int*            degarr   = (int*)(w + oDeg);
  float*          deg_inv  = (float*)(w + oDinv);
  unsigned*       coarse   = (unsigned*)(w + oBin);
  int*            colidx   = (int*)(w + oCol);
  unsigned short* P        = (unsigned short*)(w + oP);   // bf16 t buffer
  unsigned short* X        = (unsigned short*)(w + oX);   // bf16 h buffer
  float*          R        = (float*)(w + oR);            // fp32 r buffer

  hipMemsetAsync(bcur, 0, (size_t)NSB * 4, stream);

  int bbl = (E + CHK - 1) / CHK;   // 782
  bin_coarse<<<bbl, 256, 0, stream>>>(srcv, dstv, bcur, coarse, NSB, E);
  super_csr<<<NSB, 256, 0, stream>>>(coarse, bcur, rowstart, degarr, deg_inv, colidx, N);
  cvt_bf16<<<(N * 64 / 4 + 255) / 256, 256, 0, stream>>>(x, X, N * 64);

  int gb = (N + 63) / 64;
  gemm_mfma<64><<<gb, 256, 0, stream>>>(X, Wl0, Wr0, b0, P, R, N);
  gather_mean<64, true, true><<<(N + 15) / 16, 256, 0, stream>>>(
      (const uint2*)P, R, deg_inv, rowstart, degarr, colidx, X, N);
  gemm_mfma<64><<<gb, 256, 0, stream>>>(X, Wl1, Wr1, b1, P, R, N);
  gather_mean<64, true, true><<<(N + 15) / 16, 256, 0, stream>>>(
      (const uint2*)P, R, deg_inv, rowstart, degarr, colidx, X, N);
  gemm_mfma<32><<<gb, 256, 0, stream>>>(X, Wl2, Wr2, b2, P, out, N);
  gather_mean<32, false, false><<<(N + 31) / 32, 256, 0, stream>>>(
      (const uint2*)P, out, deg_inv, rowstart, degarr, colidx, out, N);
}